// Round 2
// baseline (687.058 us; speedup 1.0000x reference)
//
#include <hip/hip_runtime.h>

#define B_TOT   65536
#define DIN     1024
#define NNODES  255
#define NPAD    256
#define DOUT    128
#define BM      128
#define BK      64
#define NKT     (DIN / BK)   // 16 K-tiles

typedef __attribute__((ext_vector_type(8))) _Float16      f16x8;
typedef __attribute__((ext_vector_type(4))) float         f32x4;
typedef __attribute__((ext_vector_type(4))) unsigned short u16x4;
typedef __attribute__((ext_vector_type(8))) unsigned short u16x8;
typedef unsigned short u16;
typedef unsigned int   u32;

__device__ __forceinline__ u16 f2h(float f) {
  _Float16 h = (_Float16)f;
  return __builtin_bit_cast(u16, h);
}
__device__ __forceinline__ float h2f(u16 b) {
  return (float)__builtin_bit_cast(_Float16, b);
}
// packed fp32x2 -> fp16x2 (v_cvt_pkrtz_f16_f32), returned as u32
__device__ __forceinline__ u32 pk2h(float a, float b) {
  return __builtin_bit_cast(u32, __builtin_amdgcn_cvt_pkrtz(a, b));
}

// XOR-swizzled index into a [rows][64] fp16 tile (row stride 64 elems = 128B).
__device__ __forceinline__ int swz64(int row, int col) {
  return (row << 6) + ((((col >> 3) ^ row) & 7) << 3) + (col & 7);
}
// Same idea for the [128][256] P/probs tile (row stride 256 elems = 512B).
__device__ __forceinline__ int swzP(int row, int col) {
  int g = col >> 3;
  int gs = (g & ~7) | ((g ^ row) & 7);
  return (row << 8) + (gs << 3) + (col & 7);
}

// W (DIN x NNODES fp32) -> WtG: fragment-ordered fp16 so GEMM1 B-frags are
// direct coalesced 16B/lane global loads (L2-resident, 512 KB total).
// Frag addr (elems): ((((kc*4 + wn)*4 + nt)*2 + ks)*64 + quad*16 + l15)*8 + j
// holds W[kc*64 + ks*32 + quad*8 + j][wn*64 + nt*16 + l15].
__global__ void prep_w(const float* __restrict__ Wsp, u16* __restrict__ WtG) {
  __shared__ float t[64][65];
  const int tid = threadIdx.x;
  const int wn = blockIdx.x;        // node tile (4)
  const int kc = blockIdx.y;        // k tile   (16)
  const int bn = wn * 64, bk = kc * 64;
  {
    int n = tid & 63, kr0 = tid >> 6;
    #pragma unroll
    for (int i = 0; i < 16; ++i) {
      int k = kr0 + i * 4;
      int node = bn + n;
      t[k][n] = (node < NNODES) ? Wsp[(size_t)(bk + k) * NNODES + node] : 0.0f;
    }
  }
  __syncthreads();
  #pragma unroll
  for (int half = 0; half < 2; ++half) {
    int f = half * 256 + tid;              // frag id 0..511 within (kc,wn)
    int nt = f >> 7, rem = f & 127;
    int ks = rem >> 6, rem2 = rem & 63;
    int quad = rem2 >> 4, l15 = rem2 & 15;
    int nl = nt * 16 + l15;
    u16x8 v;
    #pragma unroll
    for (int j = 0; j < 8; ++j)
      v[j] = f2h(t[ks * 32 + quad * 8 + j][nl]);
    size_t F = (size_t)((((kc * 4 + wn) * 4 + nt) * 2 + ks) * 64 + (quad * 16 + l15));
    *(u16x8*)&WtG[F * 8] = v;
  }
}

__global__ void prep_leaf(const float* __restrict__ leaf, u16* __restrict__ lT) {
  int t = blockIdx.x * 256 + threadIdx.x;       // 32768 = 128 j x 256 leaves
  int j = t & 127, l = t >> 7;
  lT[j * NPAD + l] = f2h(leaf[l * DOUT + j]);   // coalesced read over j
}

// Sum the 4096 per-wave reg partials -> regp (scaled). One tiny block.
__global__ void finalize(const float* __restrict__ pw, float* __restrict__ regp) {
  int t = threadIdx.x;              // 512 threads, 8 partials each
  float s = 0.0f;
  #pragma unroll
  for (int i = 0; i < 8; ++i) s += pw[i * 512 + t];
  #pragma unroll
  for (int off = 32; off > 0; off >>= 1) s += __shfl_down(s, off, 64);
  __shared__ float red[8];
  if ((t & 63) == 0) red[t >> 6] = s;
  __syncthreads();
  if (t == 0) {
    float tot = 0.0f;
    #pragma unroll
    for (int i = 0; i < 8; ++i) tot += red[i];
    *regp = tot * (-0.5f / 65536.0f);
  }
}

__global__ __launch_bounds__(512, 4) void fused_sdt(
    const float* __restrict__ x, const float* __restrict__ bsp,
    const u16* __restrict__ WtG, const u16* __restrict__ lT,
    float* __restrict__ out, float* __restrict__ pw)
{
  // LDS (65536 B):
  //   GEMM1: xs0 [0,16384) + xs1 [16384,32768)   (double-buffered x tile)
  //   after GEMM1: PB [0,65536)  (P fp16, then probs fp16 in place)
  __shared__ char smem[65536] __attribute__((aligned(16)));
  u16* xs0 = (u16*)smem;            // [128][64] swizzled fp16
  u16* xs1 = xs0 + 8192;
  u16* PB  = (u16*)smem;            // [128][256] swizzled fp16

  const int tid  = threadIdx.x;
  const int lane = tid & 63;
  const int w    = tid >> 6;        // 8 waves
  const int l15  = lane & 15;
  const int quad = lane >> 4;
  const int wm   = w >> 2;          // M half   (0..1)
  const int wn   = w & 3;           // N quarter(0..3)
  const int blk  = blockIdx.x;

  const float* xg = x + (size_t)blk * BM * DIN;

  f32x4 acc[4][4];
  #pragma unroll
  for (int mt = 0; mt < 4; ++mt)
    #pragma unroll
    for (int nt = 0; nt < 4; ++nt) {
      f32x4 z = {0.0f, 0.0f, 0.0f, 0.0f};
      acc[mt][nt] = z;
    }

  // ---- W register pipeline: preload K-tile 0 fragments (issues earliest) ----
  f16x8 BfA[8], BfB[8];             // [ks*4+nt]
  {
    const u16* wb = WtG + (size_t)wn * 4096;
    #pragma unroll
    for (int q = 0; q < 8; ++q)
      BfA[q] = *(const f16x8*)&wb[(q & 3) * 1024 + (q >> 2) * 512 + lane * 8];
  }

  // ---- prologue: stage x tile 0 (512 thr x 4 float4) ----
  {
    #pragma unroll
    for (int i = 0; i < 4; ++i) {
      int idx = i * 512 + tid;
      int row = idx >> 4, kg = idx & 15;
      float4 v = *(const float4*)(xg + (size_t)row * DIN + kg * 4);
      u32 lo = pk2h(v.x, v.y);
      u32 hi = pk2h(v.z, v.w);
      u16x4 h;
      h.x = lo & 0xffff; h.y = lo >> 16;
      h.z = hi & 0xffff; h.w = hi >> 16;
      *(u16x4*)&xs0[swz64(row, kg * 4)] = h;
    }
  }
  __syncthreads();

  // ---------------- GEMM1: z = x @ W  (M=128, N=256, K=1024) ----------------
  // W frags register-pipelined one K-tile ahead (direct from L2-resident WtG).
  // x double-buffered in LDS: prefetch tile kc+1 at top, convert before barrier.
  u16* xcur = xs0;
  u16* xnxt = xs1;
  auto ktile = [&](f16x8 (&Bc)[8], f16x8 (&Bn)[8], int kc) {
    const bool pf = (kc + 1 < NKT);
    if (pf) {                          // 1. issue next-tile W frag loads
      const u16* wb = WtG + (size_t)(kc + 1) * 16384 + (size_t)wn * 4096;
      #pragma unroll
      for (int q = 0; q < 8; ++q)
        Bn[q] = *(const f16x8*)&wb[(q & 3) * 1024 + (q >> 2) * 512 + lane * 8];
    }
    float4 xv[4];
    if (pf) {                          // 2. issue next x tile loads
      #pragma unroll
      for (int i = 0; i < 4; ++i) {
        int idx = i * 512 + tid;
        int row = idx >> 4, kg = idx & 15;
        xv[i] = *(const float4*)(xg + (size_t)row * DIN + (kc + 1) * BK + kg * 4);
      }
    }
    __builtin_amdgcn_s_setprio(1);     // 3. MFMA on current tile
    #pragma unroll
    for (int ks = 0; ks < 2; ++ks) {
      const int kk = ks * 32 + quad * 8;
      f16x8 A[4];
      #pragma unroll
      for (int mt = 0; mt < 4; ++mt)
        A[mt] = *(const f16x8*)&xcur[swz64(wm * 64 + mt * 16 + l15, kk)];
      #pragma unroll
      for (int mt = 0; mt < 4; ++mt)
        #pragma unroll
        for (int nt = 0; nt < 4; ++nt)
          acc[mt][nt] = __builtin_amdgcn_mfma_f32_16x16x32_f16(
              A[mt], Bc[ks * 4 + nt], acc[mt][nt], 0, 0, 0);
    }
    __builtin_amdgcn_s_setprio(0);
    if (pf) {                          // 4. convert + publish next x tile
      #pragma unroll
      for (int i = 0; i < 4; ++i) {
        int idx = i * 512 + tid;
        int row = idx >> 4, kg = idx & 15;
        u32 lo = pk2h(xv[i].x, xv[i].y);
        u32 hi = pk2h(xv[i].z, xv[i].w);
        u16x4 h;
        h.x = lo & 0xffff; h.y = lo >> 16;
        h.z = hi & 0xffff; h.w = hi >> 16;
        *(u16x4*)&xnxt[swz64(row, kg * 4)] = h;
      }
    }
    __syncthreads();                   // xs[nxt] published; reads of xcur done
    u16* tsw = xcur; xcur = xnxt; xnxt = tsw;
  };
  for (int kc = 0; kc < NKT; kc += 2) {
    ktile(BfA, BfB, kc);
    ktile(BfB, BfA, kc + 1);
  }

  // ------------- epilogue 1: sigmoid, reg partial, P -> LDS fp16 -------------
  float rsum = 0.0f;
  float bv[4];
  #pragma unroll
  for (int nt = 0; nt < 4; ++nt) {
    int c = wn * 64 + nt * 16 + l15;
    bv[nt] = (c < NNODES) ? bsp[c] : 0.0f;
  }
  #pragma unroll
  for (int mt = 0; mt < 4; ++mt) {
    #pragma unroll
    for (int nt = 0; nt < 4; ++nt) {
      int c = wn * 64 + nt * 16 + l15;
      #pragma unroll
      for (int r = 0; r < 4; ++r) {
        int row = wm * 64 + mt * 16 + quad * 4 + r;
        float z = acc[mt][nt][r] + bv[nt];
        float e = __expf(-z);
        float p = __builtin_amdgcn_rcpf(1.0f + e);
        PB[swzP(row, c)] = f2h(p);
        if (c < NNODES) {
          float v = fmaxf(p * (1.0f - p), 1e-5f);
          int d = 31 - __clz(c + 1);                       // depth of node c
          float wgt = __builtin_bit_cast(float, (u32)(127 - d) << 23);  // 2^-d
          rsum += wgt * __logf(v);
        }
      }
    }
  }
  #pragma unroll
  for (int off = 32; off > 0; off >>= 1) rsum += __shfl_down(rsum, off, 64);
  // plain per-wave store, distinct addresses: no contention, fire-and-forget
  if (lane == 0) pw[blk * 8 + w] = rsum;
  __syncthreads();   // publishes PB to all waves

  // ------------- tree: leaf path products, overwrite PB in place -------------
  // wave w owns rows [16w,16w+16); per row, lane l computes leaves 4l..4l+3.
  // DS ops are in-order per wave: all reads of row issue before the write.
  for (int rr = 0; rr < 16; ++rr) {
    int row = (w << 4) + rr;
    float prod = 1.0f;
    #pragma unroll
    for (int d = 0; d < 6; ++d) {
      int node = (1 << d) - 1 + (lane >> (6 - d));
      float pv = h2f(PB[swzP(row, node)]);
      prod *= ((lane >> (5 - d)) & 1) ? pv : (1.0f - pv);
    }
    float p6  = h2f(PB[swzP(row, 63 + lane)]);
    float p7a = h2f(PB[swzP(row, 127 + 2 * lane)]);
    float p7b = h2f(PB[swzP(row, 128 + 2 * lane)]);
    float a0 = prod * (1.0f - p6), a1 = prod * p6;
    u16x4 o;
    o.x = f2h(a0 * (1.0f - p7a));
    o.y = f2h(a0 * p7a);
    o.z = f2h(a1 * (1.0f - p7b));
    o.w = f2h(a1 * p7b);
    *(u16x4*)&PB[swzP(row, 4 * lane)] = o;
  }
  __syncthreads();   // GEMM2 A-frags read rows written by other waves

  // -------- GEMM2: out = probs @ leaf  (128 x 128, K=256), barrier-free ------
  // B frags come straight from global lT (64 KB, L2-resident across blocks).
  f32x4 acc2[4][2];
  #pragma unroll
  for (int mt = 0; mt < 4; ++mt)
    #pragma unroll
    for (int nt = 0; nt < 2; ++nt) {
      f32x4 z = {0.0f, 0.0f, 0.0f, 0.0f};
      acc2[mt][nt] = z;
    }
  for (int kc = 0; kc < 4; ++kc) {
    #pragma unroll
    for (int ks = 0; ks < 2; ++ks) {
      const int kk = kc * 64 + ks * 32 + quad * 8;
      f16x8 Af[4], Bf2[2];
      #pragma unroll
      for (int nt = 0; nt < 2; ++nt)
        Bf2[nt] = *(const f16x8*)&lT[(wn * 32 + nt * 16 + l15) * NPAD + kk];
      #pragma unroll
      for (int mt = 0; mt < 4; ++mt)
        Af[mt] = *(const f16x8*)&PB[swzP(wm * 64 + mt * 16 + l15, kk)];
      #pragma unroll
      for (int mt = 0; mt < 4; ++mt)
        #pragma unroll
        for (int nt = 0; nt < 2; ++nt)
          acc2[mt][nt] = __builtin_amdgcn_mfma_f32_16x16x32_f16(
              Af[mt], Bf2[nt], acc2[mt][nt], 0, 0, 0);
    }
  }
  #pragma unroll
  for (int mt = 0; mt < 4; ++mt)
    #pragma unroll
    for (int nt = 0; nt < 2; ++nt)
      #pragma unroll
      for (int r = 0; r < 4; ++r) {
        int row = wm * 64 + mt * 16 + quad * 4 + r;
        int col = wn * 32 + nt * 16 + l15;
        out[(size_t)(blk * BM + row) * DOUT + col] = acc2[mt][nt][r];
      }
}

extern "C" void kernel_launch(void* const* d_in, const int* in_sizes, int n_in,
                              void* d_out, int out_size, void* d_ws, size_t ws_size,
                              hipStream_t stream) {
  (void)in_sizes; (void)n_in; (void)out_size; (void)ws_size;
  const float* x    = (const float*)d_in[0];
  const float* Wsp  = (const float*)d_in[1];
  const float* bsp  = (const float*)d_in[2];
  const float* leaf = (const float*)d_in[3];
  float* out  = (float*)d_out;
  float* regp = out + (size_t)B_TOT * DOUT;

  u16* WtG = (u16*)d_ws;                // 16 tiles x 16384 fp16 = 512 KB (frag-ordered)
  u16* lT  = WtG + NPAD * DIN;          // [128][256]  fp16 = 64 KB
  float* pw = (float*)(lT + NPAD * DOUT);  // 4096 per-wave reg partials = 16 KB

  prep_w<<<dim3(4, 16), 256, 0, stream>>>(Wsp, WtG);
  prep_leaf<<<(NPAD * DOUT) / 256, 256, 0, stream>>>(leaf, lT);
  fused_sdt<<<B_TOT / BM, 512, 0, stream>>>(x, bsp, WtG, lT, out, pw);
  finalize<<<1, 512, 0, stream>>>(pw, regp);
}

// Round 6
// 437.182 us; speedup vs baseline: 1.5716x; 1.5716x over previous
//
#include <hip/hip_runtime.h>

#define B_TOT   65536
#define DIN     1024
#define NNODES  255
#define NPAD    256
#define DOUT    128
#define BM      128
#define BK      64
#define NKT     (DIN / BK)   // 16 K-tiles

typedef __attribute__((ext_vector_type(8))) _Float16      f16x8;
typedef __attribute__((ext_vector_type(4))) float         f32x4;
typedef __attribute__((ext_vector_type(4))) unsigned short u16x4;
typedef __attribute__((ext_vector_type(8))) unsigned short u16x8;
typedef unsigned short u16;
typedef unsigned int   u32;

__device__ __forceinline__ u16 f2h(float f) {
  _Float16 h = (_Float16)f;
  return __builtin_bit_cast(u16, h);
}
__device__ __forceinline__ float h2f(u16 b) {
  return (float)__builtin_bit_cast(_Float16, b);
}
// packed fp32x2 -> fp16x2 (v_cvt_pkrtz_f16_f32), returned as u32
__device__ __forceinline__ u32 pk2h(float a, float b) {
  return __builtin_bit_cast(u32, __builtin_amdgcn_cvt_pkrtz(a, b));
}

// XOR-swizzled index into a [rows][64] fp16 tile (row stride 64 elems = 128B).
__device__ __forceinline__ int swz64(int row, int col) {
  return (row << 6) + ((((col >> 3) ^ row) & 7) << 3) + (col & 7);
}
// Same idea for the [128][256] P/probs tile (row stride 256 elems = 512B).
__device__ __forceinline__ int swzP(int row, int col) {
  int g = col >> 3;
  int gs = (g & ~7) | ((g ^ row) & 7);
  return (row << 8) + (gs << 3) + (col & 7);
}

// W (DIN x NNODES fp32) -> WtG: fragment-ordered fp16 so GEMM1 B-frags are
// direct coalesced 16B/lane global loads (L2-resident, 512 KB total).
// Frag addr (elems): ((((kc*4 + wn)*4 + nt)*2 + ks)*64 + quad*16 + l15)*8 + j
// holds W[kc*64 + ks*32 + quad*8 + j][wn*64 + nt*16 + l15].
__global__ void prep_w(const float* __restrict__ Wsp, u16* __restrict__ WtG) {
  __shared__ float t[64][65];
  const int tid = threadIdx.x;
  const int wn = blockIdx.x;        // node tile (4)
  const int kc = blockIdx.y;        // k tile   (16)
  const int bn = wn * 64, bk = kc * 64;
  {
    int n = tid & 63, kr0 = tid >> 6;
    #pragma unroll
    for (int i = 0; i < 16; ++i) {
      int k = kr0 + i * 4;
      int node = bn + n;
      t[k][n] = (node < NNODES) ? Wsp[(size_t)(bk + k) * NNODES + node] : 0.0f;
    }
  }
  __syncthreads();
  #pragma unroll
  for (int half = 0; half < 2; ++half) {
    int f = half * 256 + tid;              // frag id 0..511 within (kc,wn)
    int nt = f >> 7, rem = f & 127;
    int ks = rem >> 6, rem2 = rem & 63;
    int quad = rem2 >> 4, l15 = rem2 & 15;
    int nl = nt * 16 + l15;
    u16x8 v;
    #pragma unroll
    for (int j = 0; j < 8; ++j)
      v[j] = f2h(t[ks * 32 + quad * 8 + j][nl]);
    size_t F = (size_t)((((kc * 4 + wn) * 4 + nt) * 2 + ks) * 64 + (quad * 16 + l15));
    *(u16x8*)&WtG[F * 8] = v;
  }
}

__global__ void prep_leaf(const float* __restrict__ leaf, u16* __restrict__ lT) {
  int t = blockIdx.x * 256 + threadIdx.x;       // 32768 = 128 j x 256 leaves
  int j = t & 127, l = t >> 7;
  lT[j * NPAD + l] = f2h(leaf[l * DOUT + j]);   // coalesced read over j
}

// Sum the 4096 per-wave reg partials -> regp (scaled). One tiny block.
__global__ void finalize(const float* __restrict__ pw, float* __restrict__ regp) {
  int t = threadIdx.x;              // 512 threads, 8 partials each
  float s = 0.0f;
  #pragma unroll
  for (int i = 0; i < 8; ++i) s += pw[i * 512 + t];
  #pragma unroll
  for (int off = 32; off > 0; off >>= 1) s += __shfl_down(s, off, 64);
  __shared__ float red[8];
  if ((t & 63) == 0) red[t >> 6] = s;
  __syncthreads();
  if (t == 0) {
    float tot = 0.0f;
    #pragma unroll
    for (int i = 0; i < 8; ++i) tot += red[i];
    *regp = tot * (-0.5f / 65536.0f);
  }
}

__global__ __launch_bounds__(512, 4) void fused_sdt(
    const float* __restrict__ x, const float* __restrict__ bsp,
    const u16* __restrict__ WtG, const u16* __restrict__ lT,
    float* __restrict__ out, float* __restrict__ pw)
{
  // LDS (65536 B):
  //   GEMM1: xs0 [0,16384) + xs1 [16384,32768)   (double-buffered x tile)
  //   after GEMM1: PB [0,65536)  (P fp16, then probs fp16 in place)
  __shared__ char smem[65536] __attribute__((aligned(16)));
  u16* xs0 = (u16*)smem;            // [128][64] swizzled fp16
  u16* xs1 = xs0 + 8192;
  u16* PB  = (u16*)smem;            // [128][256] swizzled fp16

  const int tid  = threadIdx.x;
  const int lane = tid & 63;
  const int w    = tid >> 6;        // 8 waves
  const int l15  = lane & 15;
  const int quad = lane >> 4;
  const int wm   = w >> 2;          // M half   (0..1)
  const int wn   = w & 3;           // N quarter(0..3)
  const int blk  = blockIdx.x;

  const float* xg = x + (size_t)blk * BM * DIN;

  f32x4 acc[4][4];
  #pragma unroll
  for (int mt = 0; mt < 4; ++mt)
    #pragma unroll
    for (int nt = 0; nt < 4; ++nt) {
      f32x4 z = {0.0f, 0.0f, 0.0f, 0.0f};
      acc[mt][nt] = z;
    }

  // ---- prologue: stage x tile 0 (512 thr x 4 float4) ----
  {
    #pragma unroll
    for (int i = 0; i < 4; ++i) {
      int idx = i * 512 + tid;
      int row = idx >> 4, kg = idx & 15;
      float4 v = *(const float4*)(xg + (size_t)row * DIN + kg * 4);
      u32 lo = pk2h(v.x, v.y);
      u32 hi = pk2h(v.z, v.w);
      u16x4 h;
      h.x = lo & 0xffff; h.y = lo >> 16;
      h.z = hi & 0xffff; h.w = hi >> 16;
      *(u16x4*)&xs0[swz64(row, kg * 4)] = h;
    }
  }
  __syncthreads();

  // ---------------- GEMM1: z = x @ W  (M=128, N=256, K=1024) ----------------
  // W B-frags straight from global (L2-resident, coalesced 16B/lane).
  // x double-buffered: prefetch tile kc+1 at top, convert+write before barrier.
  u16* xcur = xs0;
  u16* xnxt = xs1;
  for (int kc = 0; kc < NKT; ++kc) {
    float4 xv[4];
    const bool pf = (kc + 1 < NKT);
    if (pf) {
      #pragma unroll
      for (int i = 0; i < 4; ++i) {
        int idx = i * 512 + tid;
        int row = idx >> 4, kg = idx & 15;
        xv[i] = *(const float4*)(xg + (size_t)row * DIN + (kc + 1) * BK + kg * 4);
      }
    }
    const u16* wbase = WtG + (size_t)kc * 16384 + (size_t)wn * 4096;
    __builtin_amdgcn_s_setprio(1);
    #pragma unroll
    for (int ks = 0; ks < 2; ++ks) {
      const int kk = ks * 32 + quad * 8;
      f16x8 A[4], Bf[4];
      #pragma unroll
      for (int nt = 0; nt < 4; ++nt)
        Bf[nt] = *(const f16x8*)&wbase[nt * 1024 + ks * 512 + lane * 8];
      #pragma unroll
      for (int mt = 0; mt < 4; ++mt)
        A[mt] = *(const f16x8*)&xcur[swz64(wm * 64 + mt * 16 + l15, kk)];
      #pragma unroll
      for (int mt = 0; mt < 4; ++mt)
        #pragma unroll
        for (int nt = 0; nt < 4; ++nt)
          acc[mt][nt] = __builtin_amdgcn_mfma_f32_16x16x32_f16(
              A[mt], Bf[nt], acc[mt][nt], 0, 0, 0);
    }
    __builtin_amdgcn_s_setprio(0);
    if (pf) {
      #pragma unroll
      for (int i = 0; i < 4; ++i) {
        int idx = i * 512 + tid;
        int row = idx >> 4, kg = idx & 15;
        u32 lo = pk2h(xv[i].x, xv[i].y);
        u32 hi = pk2h(xv[i].z, xv[i].w);
        u16x4 h;
        h.x = lo & 0xffff; h.y = lo >> 16;
        h.z = hi & 0xffff; h.w = hi >> 16;
        *(u16x4*)&xnxt[swz64(row, kg * 4)] = h;
      }
    }
    __syncthreads();                 // xs[nxt] published; all reads of xcur done
    u16* tsw = xcur; xcur = xnxt; xnxt = tsw;
  }

  // ------------- epilogue 1: sigmoid, reg partial, P -> LDS fp16 -------------
  float rsum = 0.0f;
  float bv[4];
  #pragma unroll
  for (int nt = 0; nt < 4; ++nt) {
    int c = wn * 64 + nt * 16 + l15;
    bv[nt] = (c < NNODES) ? bsp[c] : 0.0f;
  }
  #pragma unroll
  for (int mt = 0; mt < 4; ++mt) {
    #pragma unroll
    for (int nt = 0; nt < 4; ++nt) {
      int c = wn * 64 + nt * 16 + l15;
      #pragma unroll
      for (int r = 0; r < 4; ++r) {
        int row = wm * 64 + mt * 16 + quad * 4 + r;
        float z = acc[mt][nt][r] + bv[nt];
        float e = __expf(-z);
        float p = __builtin_amdgcn_rcpf(1.0f + e);
        PB[swzP(row, c)] = f2h(p);
        if (c < NNODES) {
          float v = fmaxf(p * (1.0f - p), 1e-5f);
          int d = 31 - __clz(c + 1);                       // depth of node c
          float wgt = __builtin_bit_cast(float, (u32)(127 - d) << 23);  // 2^-d
          rsum += wgt * __logf(v);
        }
      }
    }
  }
  #pragma unroll
  for (int off = 32; off > 0; off >>= 1) rsum += __shfl_down(rsum, off, 64);
  // plain per-wave store, distinct addresses: no contention, fire-and-forget
  if (lane == 0) pw[blk * 8 + w] = rsum;
  __syncthreads();   // publishes PB to all waves

  // ------------- tree: leaf path products, overwrite PB in place -------------
  // wave w owns rows [16w,16w+16); per row, lane l computes leaves 4l..4l+3.
  // DS ops are in-order per wave: all reads of row issue before the write.
  for (int rr = 0; rr < 16; ++rr) {
    int row = (w << 4) + rr;
    float prod = 1.0f;
    #pragma unroll
    for (int d = 0; d < 6; ++d) {
      int node = (1 << d) - 1 + (lane >> (6 - d));
      float pv = h2f(PB[swzP(row, node)]);
      prod *= ((lane >> (5 - d)) & 1) ? pv : (1.0f - pv);
    }
    float p6  = h2f(PB[swzP(row, 63 + lane)]);
    float p7a = h2f(PB[swzP(row, 127 + 2 * lane)]);
    float p7b = h2f(PB[swzP(row, 128 + 2 * lane)]);
    float a0 = prod * (1.0f - p6), a1 = prod * p6;
    u16x4 o;
    o.x = f2h(a0 * (1.0f - p7a));
    o.y = f2h(a0 * p7a);
    o.z = f2h(a1 * (1.0f - p7b));
    o.w = f2h(a1 * p7b);
    *(u16x4*)&PB[swzP(row, 4 * lane)] = o;
  }
  __syncthreads();   // GEMM2 A-frags read rows written by other waves

  // -------- GEMM2: out = probs @ leaf  (128 x 128, K=256), barrier-free ------
  // B frags come straight from global lT (64 KB, L2-resident across blocks).
  f32x4 acc2[4][2];
  #pragma unroll
  for (int mt = 0; mt < 4; ++mt)
    #pragma unroll
    for (int nt = 0; nt < 2; ++nt) {
      f32x4 z = {0.0f, 0.0f, 0.0f, 0.0f};
      acc2[mt][nt] = z;
    }
  for (int kc = 0; kc < 4; ++kc) {
    #pragma unroll
    for (int ks = 0; ks < 2; ++ks) {
      const int kk = kc * 64 + ks * 32 + quad * 8;
      f16x8 Af[4], Bf2[2];
      #pragma unroll
      for (int nt = 0; nt < 2; ++nt)
        Bf2[nt] = *(const f16x8*)&lT[(wn * 32 + nt * 16 + l15) * NPAD + kk];
      #pragma unroll
      for (int mt = 0; mt < 4; ++mt)
        Af[mt] = *(const f16x8*)&PB[swzP(wm * 64 + mt * 16 + l15, kk)];
      #pragma unroll
      for (int mt = 0; mt < 4; ++mt)
        #pragma unroll
        for (int nt = 0; nt < 2; ++nt)
          acc2[mt][nt] = __builtin_amdgcn_mfma_f32_16x16x32_f16(
              Af[mt], Bf2[nt], acc2[mt][nt], 0, 0, 0);
    }
  }
  #pragma unroll
  for (int mt = 0; mt < 4; ++mt)
    #pragma unroll
    for (int nt = 0; nt < 2; ++nt)
      #pragma unroll
      for (int r = 0; r < 4; ++r) {
        int row = wm * 64 + mt * 16 + quad * 4 + r;
        int col = wn * 32 + nt * 16 + l15;
        out[(size_t)(blk * BM + row) * DOUT + col] = acc2[mt][nt][r];
      }
}

extern "C" void kernel_launch(void* const* d_in, const int* in_sizes, int n_in,
                              void* d_out, int out_size, void* d_ws, size_t ws_size,
                              hipStream_t stream) {
  (void)in_sizes; (void)n_in; (void)out_size; (void)ws_size;
  const float* x    = (const float*)d_in[0];
  const float* Wsp  = (const float*)d_in[1];
  const float* bsp  = (const float*)d_in[2];
  const float* leaf = (const float*)d_in[3];
  float* out  = (float*)d_out;
  float* regp = out + (size_t)B_TOT * DOUT;

  u16* WtG = (u16*)d_ws;                // 16 tiles x 16384 fp16 = 512 KB (frag-ordered)
  u16* lT  = WtG + NPAD * DIN;          // [128][256]  fp16 = 64 KB
  float* pw = (float*)(lT + NPAD * DOUT);  // 4096 per-wave reg partials = 16 KB

  prep_w<<<dim3(4, 16), 256, 0, stream>>>(Wsp, WtG);
  prep_leaf<<<(NPAD * DOUT) / 256, 256, 0, stream>>>(leaf, lT);
  fused_sdt<<<B_TOT / BM, 512, 0, stream>>>(x, bsp, WtG, lT, out, pw);
  finalize<<<1, 512, 0, stream>>>(pw, regp);
}

// Round 7
// 422.545 us; speedup vs baseline: 1.6260x; 1.0346x over previous
//
#include <hip/hip_runtime.h>

#define B_TOT   65536
#define DIN     1024
#define NNODES  255
#define NPAD    256
#define DOUT    128
#define BM      128
#define BK      64
#define NKT     (DIN / BK)   // 16 K-tiles

typedef __attribute__((ext_vector_type(8))) _Float16      f16x8;
typedef __attribute__((ext_vector_type(4))) float         f32x4;
typedef __attribute__((ext_vector_type(4))) unsigned short u16x4;
typedef __attribute__((ext_vector_type(8))) unsigned short u16x8;
typedef __attribute__((ext_vector_type(4))) unsigned int   u32x4;
typedef unsigned short u16;
typedef unsigned int   u32;

__device__ __forceinline__ u16 f2h(float f) {
  _Float16 h = (_Float16)f;
  return __builtin_bit_cast(u16, h);
}
__device__ __forceinline__ float h2f(u16 b) {
  return (float)__builtin_bit_cast(_Float16, b);
}
// packed fp32x2 -> fp16x2 (v_cvt_pkrtz_f16_f32), returned as u32
__device__ __forceinline__ u32 pk2h(float a, float b) {
  return __builtin_bit_cast(u32, __builtin_amdgcn_cvt_pkrtz(a, b));
}
// async 16B global->LDS DMA; LDS dest is wave-uniform base + lane*16
__device__ __forceinline__ void cp16_g2s(const float* g, float* l) {
  __builtin_amdgcn_global_load_lds(
      (const __attribute__((address_space(1))) unsigned int*)g,
      (__attribute__((address_space(3))) unsigned int*)l, 16, 0, 0);
}

// [128][256] P/probs fp16 tile swizzle (row stride 256 elems = 512B).
__device__ __forceinline__ int swzP(int row, int col) {
  int g = col >> 3;
  int gs = (g & ~7) | ((g ^ row) & 7);
  return (row << 8) + (gs << 3) + (col & 7);
}

// W (DIN x NNODES fp32) -> WtG: fragment-ordered fp16 so GEMM1 B-frags are
// direct coalesced 16B/lane global loads (L2-resident, 512 KB total).
// Frag addr (elems): ((((kc*4 + wn)*4 + nt)*2 + ks)*64 + quad*16 + l15)*8 + j
// holds W[kc*64 + ks*32 + quad*8 + j][wn*64 + nt*16 + l15].
__global__ void prep_w(const float* __restrict__ Wsp, u16* __restrict__ WtG) {
  __shared__ float t[64][65];
  const int tid = threadIdx.x;
  const int wn = blockIdx.x;        // node tile (4)
  const int kc = blockIdx.y;        // k tile   (16)
  const int bn = wn * 64, bk = kc * 64;
  {
    int n = tid & 63, kr0 = tid >> 6;
    #pragma unroll
    for (int i = 0; i < 16; ++i) {
      int k = kr0 + i * 4;
      int node = bn + n;
      t[k][n] = (node < NNODES) ? Wsp[(size_t)(bk + k) * NNODES + node] : 0.0f;
    }
  }
  __syncthreads();
  #pragma unroll
  for (int half = 0; half < 2; ++half) {
    int f = half * 256 + tid;              // frag id 0..511 within (kc,wn)
    int nt = f >> 7, rem = f & 127;
    int ks = rem >> 6, rem2 = rem & 63;
    int quad = rem2 >> 4, l15 = rem2 & 15;
    int nl = nt * 16 + l15;
    u16x8 v;
    #pragma unroll
    for (int j = 0; j < 8; ++j)
      v[j] = f2h(t[ks * 32 + quad * 8 + j][nl]);
    size_t F = (size_t)((((kc * 4 + wn) * 4 + nt) * 2 + ks) * 64 + (quad * 16 + l15));
    *(u16x8*)&WtG[F * 8] = v;
  }
}

__global__ void prep_leaf(const float* __restrict__ leaf, u16* __restrict__ lT) {
  int t = blockIdx.x * 256 + threadIdx.x;       // 32768 = 128 j x 256 leaves
  int j = t & 127, l = t >> 7;
  lT[j * NPAD + l] = f2h(leaf[l * DOUT + j]);   // coalesced read over j
}

// Sum the 4096 per-wave reg partials -> regp (scaled). One tiny block.
__global__ void finalize(const float* __restrict__ pw, float* __restrict__ regp) {
  int t = threadIdx.x;              // 512 threads, 8 partials each
  float s = 0.0f;
  #pragma unroll
  for (int i = 0; i < 8; ++i) s += pw[i * 512 + t];
  #pragma unroll
  for (int off = 32; off > 0; off >>= 1) s += __shfl_down(s, off, 64);
  __shared__ float red[8];
  if ((t & 63) == 0) red[t >> 6] = s;
  __syncthreads();
  if (t == 0) {
    float tot = 0.0f;
    #pragma unroll
    for (int i = 0; i < 8; ++i) tot += red[i];
    *regp = tot * (-0.5f / 65536.0f);
  }
}

__global__ __launch_bounds__(512, 4) void fused_sdt(
    const float* __restrict__ x, const float* __restrict__ bsp,
    const u16* __restrict__ WtG, const u16* __restrict__ lT,
    float* __restrict__ out, float* __restrict__ pw)
{
  // LDS (65536 B):
  //   GEMM1: xs0 [0,32768) + xs1 [32768,65536)  fp32 x tiles, double-buffered.
  //     Granule layout (16B = 4 f32): slot s -> row = s>>4, gsw = s&15 holds
  //     granule g = (gsw ^ row) & 15 of row's 64-col K-slice. LDS is written
  //     LINEARLY by global_load_lds; the swizzle lives in the per-lane GLOBAL
  //     source address (m173 pattern). Reads XOR the same way -> conflict-free.
  //   after GEMM1: PB [0,65536)  (P fp16, then probs fp16 in place)
  __shared__ char smem[65536] __attribute__((aligned(16)));
  float* xs0 = (float*)smem;        // [128 rows][64 f32] granule-swizzled
  float* xs1 = xs0 + 8192;
  u16*   PB  = (u16*)smem;          // [128][256] swizzled fp16

  const int tid  = threadIdx.x;
  const int lane = tid & 63;
  const int w    = tid >> 6;        // 8 waves
  const int l15  = lane & 15;
  const int quad = lane >> 4;
  const int wm   = w >> 2;          // M half   (0..1)
  const int wn   = w & 3;           // N quarter(0..3)
  const int blk  = blockIdx.x;

  const float* xg = x + (size_t)blk * BM * DIN;

  f32x4 acc[4][4];
  #pragma unroll
  for (int mt = 0; mt < 4; ++mt)
    #pragma unroll
    for (int nt = 0; nt < 4; ++nt) {
      f32x4 z = {0.0f, 0.0f, 0.0f, 0.0f};
      acc[mt][nt] = z;
    }

  // async-stage one 32KB fp32 x tile: wave w issues 4 gll, chunk = 64 granules
  auto stage_x = [&](float* buf, int kt) {
    #pragma unroll
    for (int i = 0; i < 4; ++i) {
      int s   = (w * 4 + i) * 64 + lane;    // granule slot this lane fills
      int row = s >> 4;
      int g   = ((s & 15) ^ row) & 15;      // which granule belongs here
      cp16_g2s(xg + (size_t)row * DIN + kt * BK + g * 4,
               buf + (w * 4 + i) * 256);    // uniform chunk base (HW adds lane*16)
    }
  };

  // ---- prologue: stage x tile 0 ----
  stage_x(xs0, 0);
  __syncthreads();                          // drains gll (vmcnt 0)

  // ---------------- GEMM1: z = x @ W  (M=128, N=256, K=1024) ----------------
  // Load-issue ORDER is the point (vmcnt is FIFO, m135): per kc we issue the
  // 8 W-frag loads FIRST, then the 4 gll-x for kc+1. MFMA ks0 then needs only
  // vmcnt(8) (x + Bf-ks1 still in flight), ks1 needs vmcnt(4); only the
  // end-of-tile barrier drains the async x staging.
  float* xcur = xs0;
  float* xnxt = xs1;
  for (int kc = 0; kc < NKT; ++kc) {
    // 1. W frags for THIS kc (L2-resident, coalesced 16B/lane)
    f16x8 Bf[8];                            // [ks*4+nt]
    {
      const u16* wbase = WtG + (size_t)kc * 16384 + (size_t)wn * 4096;
      #pragma unroll
      for (int q = 0; q < 8; ++q)
        Bf[q] = *(const f16x8*)&wbase[(q & 3) * 1024 + (q >> 2) * 512 + lane * 8];
    }
    // 2. async-stage x tile kc+1 (no VGPRs, no staging VALU)
    if (kc + 1 < NKT) stage_x(xnxt, kc + 1);
    // 3. MFMA on current tile; A-frags converted fp32->fp16 at load time
    __builtin_amdgcn_s_setprio(1);
    #pragma unroll
    for (int ks = 0; ks < 2; ++ks) {
      const int g0 = ks * 8 + quad * 2;     // first granule of this lane's 8 cols
      #pragma unroll
      for (int mt = 0; mt < 4; ++mt) {
        const int row = wm * 64 + mt * 16 + l15;
        const float* rb = xcur + row * 64;
        f32x4 lo = *(const f32x4*)(rb + (((g0    ) ^ row) & 15) * 4);
        f32x4 hi = *(const f32x4*)(rb + (((g0 + 1) ^ row) & 15) * 4);
        u32x4 aw;
        aw[0] = pk2h(lo[0], lo[1]);
        aw[1] = pk2h(lo[2], lo[3]);
        aw[2] = pk2h(hi[0], hi[1]);
        aw[3] = pk2h(hi[2], hi[3]);
        f16x8 A = __builtin_bit_cast(f16x8, aw);
        #pragma unroll
        for (int nt = 0; nt < 4; ++nt)
          acc[mt][nt] = __builtin_amdgcn_mfma_f32_16x16x32_f16(
              A, Bf[ks * 4 + nt], acc[mt][nt], 0, 0, 0);
      }
    }
    __builtin_amdgcn_s_setprio(0);
    __syncthreads();                 // xnxt landed; all reads of xcur done
    float* tsw = xcur; xcur = xnxt; xnxt = tsw;
  }

  // ------------- epilogue 1: sigmoid, reg partial, P -> LDS fp16 -------------
  float rsum = 0.0f;
  float bv[4];
  #pragma unroll
  for (int nt = 0; nt < 4; ++nt) {
    int c = wn * 64 + nt * 16 + l15;
    bv[nt] = (c < NNODES) ? bsp[c] : 0.0f;
  }
  #pragma unroll
  for (int mt = 0; mt < 4; ++mt) {
    #pragma unroll
    for (int nt = 0; nt < 4; ++nt) {
      int c = wn * 64 + nt * 16 + l15;
      #pragma unroll
      for (int r = 0; r < 4; ++r) {
        int row = wm * 64 + mt * 16 + quad * 4 + r;
        float z = acc[mt][nt][r] + bv[nt];
        float e = __expf(-z);
        float p = __builtin_amdgcn_rcpf(1.0f + e);
        PB[swzP(row, c)] = f2h(p);
        if (c < NNODES) {
          float v = fmaxf(p * (1.0f - p), 1e-5f);
          int d = 31 - __clz(c + 1);                       // depth of node c
          float wgt = __builtin_bit_cast(float, (u32)(127 - d) << 23);  // 2^-d
          rsum += wgt * __logf(v);
        }
      }
    }
  }
  #pragma unroll
  for (int off = 32; off > 0; off >>= 1) rsum += __shfl_down(rsum, off, 64);
  // plain per-wave store, distinct addresses: no contention, fire-and-forget
  if (lane == 0) pw[blk * 8 + w] = rsum;
  __syncthreads();   // publishes PB to all waves

  // ------------- tree: leaf path products, overwrite PB in place -------------
  // wave w owns rows [16w,16w+16); per row, lane l computes leaves 4l..4l+3.
  // DS ops are in-order per wave: all reads of row issue before the write.
  for (int rr = 0; rr < 16; ++rr) {
    int row = (w << 4) + rr;
    float prod = 1.0f;
    #pragma unroll
    for (int d = 0; d < 6; ++d) {
      int node = (1 << d) - 1 + (lane >> (6 - d));
      float pv = h2f(PB[swzP(row, node)]);
      prod *= ((lane >> (5 - d)) & 1) ? pv : (1.0f - pv);
    }
    float p6  = h2f(PB[swzP(row, 63 + lane)]);
    float p7a = h2f(PB[swzP(row, 127 + 2 * lane)]);
    float p7b = h2f(PB[swzP(row, 128 + 2 * lane)]);
    float a0 = prod * (1.0f - p6), a1 = prod * p6;
    u16x4 o;
    o.x = f2h(a0 * (1.0f - p7a));
    o.y = f2h(a0 * p7a);
    o.z = f2h(a1 * (1.0f - p7b));
    o.w = f2h(a1 * p7b);
    *(u16x4*)&PB[swzP(row, 4 * lane)] = o;
  }
  __syncthreads();   // GEMM2 A-frags read rows written by other waves

  // -------- GEMM2: out = probs @ leaf  (128 x 128, K=256), barrier-free ------
  // B frags come straight from global lT (64 KB, L2-resident across blocks).
  f32x4 acc2[4][2];
  #pragma unroll
  for (int mt = 0; mt < 4; ++mt)
    #pragma unroll
    for (int nt = 0; nt < 2; ++nt) {
      f32x4 z = {0.0f, 0.0f, 0.0f, 0.0f};
      acc2[mt][nt] = z;
    }
  for (int kc = 0; kc < 4; ++kc) {
    #pragma unroll
    for (int ks = 0; ks < 2; ++ks) {
      const int kk = kc * 64 + ks * 32 + quad * 8;
      f16x8 Af[4], Bf2[2];
      #pragma unroll
      for (int nt = 0; nt < 2; ++nt)
        Bf2[nt] = *(const f16x8*)&lT[(wn * 32 + nt * 16 + l15) * NPAD + kk];
      #pragma unroll
      for (int mt = 0; mt < 4; ++mt)
        Af[mt] = *(const f16x8*)&PB[swzP(wm * 64 + mt * 16 + l15, kk)];
      #pragma unroll
      for (int mt = 0; mt < 4; ++mt)
        #pragma unroll
        for (int nt = 0; nt < 2; ++nt)
          acc2[mt][nt] = __builtin_amdgcn_mfma_f32_16x16x32_f16(
              Af[mt], Bf2[nt], acc2[mt][nt], 0, 0, 0);
    }
  }
  #pragma unroll
  for (int mt = 0; mt < 4; ++mt)
    #pragma unroll
    for (int nt = 0; nt < 2; ++nt)
      #pragma unroll
      for (int r = 0; r < 4; ++r) {
        int row = wm * 64 + mt * 16 + quad * 4 + r;
        int col = wn * 32 + nt * 16 + l15;
        out[(size_t)(blk * BM + row) * DOUT + col] = acc2[mt][nt][r];
      }
}

extern "C" void kernel_launch(void* const* d_in, const int* in_sizes, int n_in,
                              void* d_out, int out_size, void* d_ws, size_t ws_size,
                              hipStream_t stream) {
  (void)in_sizes; (void)n_in; (void)out_size; (void)ws_size;
  const float* x    = (const float*)d_in[0];
  const float* Wsp  = (const float*)d_in[1];
  const float* bsp  = (const float*)d_in[2];
  const float* leaf = (const float*)d_in[3];
  float* out  = (float*)d_out;
  float* regp = out + (size_t)B_TOT * DOUT;

  u16* WtG = (u16*)d_ws;                // 16 tiles x 16384 fp16 = 512 KB (frag-ordered)
  u16* lT  = WtG + NPAD * DIN;          // [128][256]  fp16 = 64 KB
  float* pw = (float*)(lT + NPAD * DOUT);  // 4096 per-wave reg partials = 16 KB

  prep_w<<<dim3(4, 16), 256, 0, stream>>>(Wsp, WtG);
  prep_leaf<<<(NPAD * DOUT) / 256, 256, 0, stream>>>(leaf, lT);
  fused_sdt<<<B_TOT / BM, 512, 0, stream>>>(x, bsp, WtG, lT, out, pw);
  finalize<<<1, 512, 0, stream>>>(pw, regp);
}

// Round 8
// 415.197 us; speedup vs baseline: 1.6548x; 1.0177x over previous
//
#include <hip/hip_runtime.h>

#define B_TOT   65536
#define DIN     1024
#define NNODES  255
#define NPAD    256
#define DOUT    128
#define BM      64
#define BK      64
#define NKT     (DIN / BK)   // 16 K-tiles

typedef __attribute__((ext_vector_type(8))) _Float16      f16x8;
typedef __attribute__((ext_vector_type(4))) float         f32x4;
typedef __attribute__((ext_vector_type(4))) unsigned short u16x4;
typedef __attribute__((ext_vector_type(8))) unsigned short u16x8;
typedef __attribute__((ext_vector_type(4))) unsigned int   u32x4;
typedef unsigned short u16;
typedef unsigned int   u32;

__device__ __forceinline__ u16 f2h(float f) {
  _Float16 h = (_Float16)f;
  return __builtin_bit_cast(u16, h);
}
__device__ __forceinline__ float h2f(u16 b) {
  return (float)__builtin_bit_cast(_Float16, b);
}
// packed fp32x2 -> fp16x2 (v_cvt_pkrtz_f16_f32), returned as u32
__device__ __forceinline__ u32 pk2h(float a, float b) {
  return __builtin_bit_cast(u32, __builtin_amdgcn_cvt_pkrtz(a, b));
}
// async 16B global->LDS DMA; LDS dest is wave-uniform base + lane*16
__device__ __forceinline__ void cp16_g2s(const float* g, float* l) {
  __builtin_amdgcn_global_load_lds(
      (const __attribute__((address_space(1))) unsigned int*)g,
      (__attribute__((address_space(3))) unsigned int*)l, 16, 0, 0);
}

// [64][256] P/probs fp16 tile swizzle (row stride 256 elems = 512B).
__device__ __forceinline__ int swzP(int row, int col) {
  int g = col >> 3;
  int gs = (g & ~7) | ((g ^ row) & 7);
  return (row << 8) + (gs << 3) + (col & 7);
}

// W (DIN x NNODES fp32) -> WtG: fragment-ordered fp16 so GEMM1 B-frags are
// direct coalesced 16B/lane global loads (L2-resident, 512 KB total).
// Frag addr (elems): ((((kc*4 + wn)*4 + nt)*2 + ks)*64 + quad*16 + l15)*8 + j
// holds W[kc*64 + ks*32 + quad*8 + j][wn*64 + nt*16 + l15].
__global__ void prep_w(const float* __restrict__ Wsp, u16* __restrict__ WtG) {
  __shared__ float t[64][65];
  const int tid = threadIdx.x;
  const int wn = blockIdx.x;        // node tile (4)
  const int kc = blockIdx.y;        // k tile   (16)
  const int bn = wn * 64, bk = kc * 64;
  {
    int n = tid & 63, kr0 = tid >> 6;
    #pragma unroll
    for (int i = 0; i < 16; ++i) {
      int k = kr0 + i * 4;
      int node = bn + n;
      t[k][n] = (node < NNODES) ? Wsp[(size_t)(bk + k) * NNODES + node] : 0.0f;
    }
  }
  __syncthreads();
  #pragma unroll
  for (int half = 0; half < 2; ++half) {
    int f = half * 256 + tid;              // frag id 0..511 within (kc,wn)
    int nt = f >> 7, rem = f & 127;
    int ks = rem >> 6, rem2 = rem & 63;
    int quad = rem2 >> 4, l15 = rem2 & 15;
    int nl = nt * 16 + l15;
    u16x8 v;
    #pragma unroll
    for (int j = 0; j < 8; ++j)
      v[j] = f2h(t[ks * 32 + quad * 8 + j][nl]);
    size_t F = (size_t)((((kc * 4 + wn) * 4 + nt) * 2 + ks) * 64 + (quad * 16 + l15));
    *(u16x8*)&WtG[F * 8] = v;
  }
}

__global__ void prep_leaf(const float* __restrict__ leaf, u16* __restrict__ lT) {
  int t = blockIdx.x * 256 + threadIdx.x;       // 32768 = 128 j x 256 leaves
  int j = t & 127, l = t >> 7;
  lT[j * NPAD + l] = f2h(leaf[l * DOUT + j]);   // coalesced read over j
}

// Sum the 4096 per-wave reg partials -> regp (scaled). One tiny block.
__global__ void finalize(const float* __restrict__ pw, float* __restrict__ regp) {
  int t = threadIdx.x;              // 512 threads, 8 partials each
  float s = 0.0f;
  #pragma unroll
  for (int i = 0; i < 8; ++i) s += pw[i * 512 + t];
  #pragma unroll
  for (int off = 32; off > 0; off >>= 1) s += __shfl_down(s, off, 64);
  __shared__ float red[8];
  if ((t & 63) == 0) red[t >> 6] = s;
  __syncthreads();
  if (t == 0) {
    float tot = 0.0f;
    #pragma unroll
    for (int i = 0; i < 8; ++i) tot += red[i];
    *regp = tot * (-0.5f / 65536.0f);
  }
}

// 4 waves/block, 32KB LDS, 4 independent blocks/CU (all 1024 resident):
// small barriers + block dephasing hide the per-kc staging drain.
__global__ __launch_bounds__(256, 4) void fused_sdt(
    const float* __restrict__ x, const float* __restrict__ bsp,
    const u16* __restrict__ WtG, const u16* __restrict__ lT,
    float* __restrict__ out, float* __restrict__ pw)
{
  // LDS (32768 B):
  //   GEMM1: xs0 [0,16384) + xs1 [16384,32768)  fp32 x tiles, double-buffered.
  //     Granule layout (16B = 4 f32): slot s -> row = s>>4, holds granule
  //     g = ((s&15) ^ row) & 15 of the row's 64-col K-slice. LDS is written
  //     LINEARLY by global_load_lds; the swizzle lives in the per-lane GLOBAL
  //     source address (m173 pattern). Reads XOR the same way -> conflict-free.
  //   after GEMM1: PB [0,32768)  (P fp16, then probs fp16 in place)
  __shared__ char smem[32768] __attribute__((aligned(16)));
  float* xs0 = (float*)smem;        // [64 rows][64 f32] granule-swizzled
  float* xs1 = xs0 + 4096;
  u16*   PB  = (u16*)smem;          // [64][256] swizzled fp16

  const int tid  = threadIdx.x;
  const int lane = tid & 63;
  const int w    = tid >> 6;        // 4 waves; wave w owns node quarter wn = w
  const int l15  = lane & 15;
  const int quad = lane >> 4;
  const int wn   = w;
  const int blk  = blockIdx.x;

  const float* xg = x + (size_t)blk * BM * DIN;

  f32x4 acc[4][4];
  #pragma unroll
  for (int mt = 0; mt < 4; ++mt)
    #pragma unroll
    for (int nt = 0; nt < 4; ++nt) {
      f32x4 z = {0.0f, 0.0f, 0.0f, 0.0f};
      acc[mt][nt] = z;
    }

  // async-stage one 16KB fp32 x tile: wave w issues 4 gll (1024 granules tot)
  auto stage_x = [&](float* buf, int kt) {
    #pragma unroll
    for (int i = 0; i < 4; ++i) {
      int s   = (w * 4 + i) * 64 + lane;    // granule slot this lane fills
      int row = s >> 4;
      int g   = ((s & 15) ^ row) & 15;      // which granule belongs here
      cp16_g2s(xg + (size_t)row * DIN + kt * BK + g * 4,
               buf + (w * 4 + i) * 256);    // uniform chunk base (HW adds lane*16)
    }
  };

  // ---- prologue: stage x tile 0 ----
  stage_x(xs0, 0);
  __syncthreads();                          // drains gll (vmcnt 0)

  // ---------------- GEMM1: z = x @ W  (M=64, N=256, K=1024) ----------------
  // Per kc, issue order (vmcnt is FIFO, m135): 8 W-frag loads FIRST (L2),
  // then 4 gll-x for kc+1 (HBM). MFMA needs only vmcnt(4); the end-of-tile
  // barrier drains the async x staging while other blocks on the CU compute.
  float* xcur = xs0;
  float* xnxt = xs1;
  for (int kc = 0; kc < NKT; ++kc) {
    // 1. W frags for THIS kc (L2-resident, coalesced 16B/lane)
    f16x8 Bf[8];                            // [ks*4+nt]
    {
      const u16* wbase = WtG + (size_t)kc * 16384 + (size_t)wn * 4096;
      #pragma unroll
      for (int q = 0; q < 8; ++q)
        Bf[q] = *(const f16x8*)&wbase[(q & 3) * 1024 + (q >> 2) * 512 + lane * 8];
    }
    // 2. async-stage x tile kc+1 (no VGPRs, no staging VALU)
    if (kc + 1 < NKT) stage_x(xnxt, kc + 1);
    // 3. MFMA on current tile; A-frags converted fp32->fp16 at load time
    __builtin_amdgcn_s_setprio(1);
    #pragma unroll
    for (int ks = 0; ks < 2; ++ks) {
      const int g0 = ks * 8 + quad * 2;     // first granule of this lane's 8 cols
      #pragma unroll
      for (int mt = 0; mt < 4; ++mt) {
        const int row = mt * 16 + l15;
        const float* rb = xcur + row * 64;
        f32x4 lo = *(const f32x4*)(rb + (((g0    ) ^ row) & 15) * 4);
        f32x4 hi = *(const f32x4*)(rb + (((g0 + 1) ^ row) & 15) * 4);
        u32x4 aw;
        aw[0] = pk2h(lo[0], lo[1]);
        aw[1] = pk2h(lo[2], lo[3]);
        aw[2] = pk2h(hi[0], hi[1]);
        aw[3] = pk2h(hi[2], hi[3]);
        f16x8 A = __builtin_bit_cast(f16x8, aw);
        #pragma unroll
        for (int nt = 0; nt < 4; ++nt)
          acc[mt][nt] = __builtin_amdgcn_mfma_f32_16x16x32_f16(
              A, Bf[ks * 4 + nt], acc[mt][nt], 0, 0, 0);
      }
    }
    __builtin_amdgcn_s_setprio(0);
    __syncthreads();                 // xnxt landed; all reads of xcur done
    float* tsw = xcur; xcur = xnxt; xnxt = tsw;
  }

  // ------------- epilogue 1: sigmoid, reg partial, P -> LDS fp16 -------------
  float rsum = 0.0f;
  float bv[4];
  #pragma unroll
  for (int nt = 0; nt < 4; ++nt) {
    int c = wn * 64 + nt * 16 + l15;
    bv[nt] = (c < NNODES) ? bsp[c] : 0.0f;
  }
  #pragma unroll
  for (int mt = 0; mt < 4; ++mt) {
    #pragma unroll
    for (int nt = 0; nt < 4; ++nt) {
      int c = wn * 64 + nt * 16 + l15;
      #pragma unroll
      for (int r = 0; r < 4; ++r) {
        int row = mt * 16 + quad * 4 + r;
        float z = acc[mt][nt][r] + bv[nt];
        float e = __expf(-z);
        float p = __builtin_amdgcn_rcpf(1.0f + e);
        PB[swzP(row, c)] = f2h(p);
        if (c < NNODES) {
          float v = fmaxf(p * (1.0f - p), 1e-5f);
          int d = 31 - __clz(c + 1);                       // depth of node c
          float wgt = __builtin_bit_cast(float, (u32)(127 - d) << 23);  // 2^-d
          rsum += wgt * __logf(v);
        }
      }
    }
  }
  #pragma unroll
  for (int off = 32; off > 0; off >>= 1) rsum += __shfl_down(rsum, off, 64);
  // plain per-wave store, distinct addresses: no contention, fire-and-forget
  if (lane == 0) pw[blk * 4 + w] = rsum;
  __syncthreads();   // publishes PB to all waves

  // ------------- tree: leaf path products, overwrite PB in place -------------
  // wave w owns rows [16w,16w+16); per row, lane l computes leaves 4l..4l+3.
  // DS ops are in-order per wave: all reads of row issue before the write.
  for (int rr = 0; rr < 16; ++rr) {
    int row = (w << 4) + rr;
    float prod = 1.0f;
    #pragma unroll
    for (int d = 0; d < 6; ++d) {
      int node = (1 << d) - 1 + (lane >> (6 - d));
      float pv = h2f(PB[swzP(row, node)]);
      prod *= ((lane >> (5 - d)) & 1) ? pv : (1.0f - pv);
    }
    float p6  = h2f(PB[swzP(row, 63 + lane)]);
    float p7a = h2f(PB[swzP(row, 127 + 2 * lane)]);
    float p7b = h2f(PB[swzP(row, 128 + 2 * lane)]);
    float a0 = prod * (1.0f - p6), a1 = prod * p6;
    u16x4 o;
    o.x = f2h(a0 * (1.0f - p7a));
    o.y = f2h(a0 * p7a);
    o.z = f2h(a1 * (1.0f - p7b));
    o.w = f2h(a1 * p7b);
    *(u16x4*)&PB[swzP(row, 4 * lane)] = o;
  }
  __syncthreads();   // GEMM2 A-frags read rows written by other waves

  // -------- GEMM2: out = probs @ leaf  (64 x 128, K=256), barrier-free ------
  // B frags come straight from global lT (64 KB, L2-resident across blocks).
  f32x4 acc2[4][2];
  #pragma unroll
  for (int mt = 0; mt < 4; ++mt)
    #pragma unroll
    for (int nt = 0; nt < 2; ++nt) {
      f32x4 z = {0.0f, 0.0f, 0.0f, 0.0f};
      acc2[mt][nt] = z;
    }
  for (int kc = 0; kc < 4; ++kc) {
    #pragma unroll
    for (int ks = 0; ks < 2; ++ks) {
      const int kk = kc * 64 + ks * 32 + quad * 8;
      f16x8 Af[4], Bf2[2];
      #pragma unroll
      for (int nt = 0; nt < 2; ++nt)
        Bf2[nt] = *(const f16x8*)&lT[(wn * 32 + nt * 16 + l15) * NPAD + kk];
      #pragma unroll
      for (int mt = 0; mt < 4; ++mt)
        Af[mt] = *(const f16x8*)&PB[swzP(mt * 16 + l15, kk)];
      #pragma unroll
      for (int mt = 0; mt < 4; ++mt)
        #pragma unroll
        for (int nt = 0; nt < 2; ++nt)
          acc2[mt][nt] = __builtin_amdgcn_mfma_f32_16x16x32_f16(
              Af[mt], Bf2[nt], acc2[mt][nt], 0, 0, 0);
    }
  }
  #pragma unroll
  for (int mt = 0; mt < 4; ++mt)
    #pragma unroll
    for (int nt = 0; nt < 2; ++nt)
      #pragma unroll
      for (int r = 0; r < 4; ++r) {
        int row = mt * 16 + quad * 4 + r;
        int col = wn * 32 + nt * 16 + l15;
        out[(size_t)(blk * BM + row) * DOUT + col] = acc2[mt][nt][r];
      }
}

extern "C" void kernel_launch(void* const* d_in, const int* in_sizes, int n_in,
                              void* d_out, int out_size, void* d_ws, size_t ws_size,
                              hipStream_t stream) {
  (void)in_sizes; (void)n_in; (void)out_size; (void)ws_size;
  const float* x    = (const float*)d_in[0];
  const float* Wsp  = (const float*)d_in[1];
  const float* bsp  = (const float*)d_in[2];
  const float* leaf = (const float*)d_in[3];
  float* out  = (float*)d_out;
  float* regp = out + (size_t)B_TOT * DOUT;

  u16* WtG = (u16*)d_ws;                // 16 tiles x 16384 fp16 = 512 KB (frag-ordered)
  u16* lT  = WtG + NPAD * DIN;          // [128][256]  fp16 = 64 KB
  float* pw = (float*)(lT + NPAD * DOUT);  // 4096 per-wave reg partials = 16 KB

  prep_w<<<dim3(4, 16), 256, 0, stream>>>(Wsp, WtG);
  prep_leaf<<<(NPAD * DOUT) / 256, 256, 0, stream>>>(leaf, lT);
  fused_sdt<<<B_TOT / BM, 256, 0, stream>>>(x, bsp, WtG, lT, out, pw);
  finalize<<<1, 512, 0, stream>>>(pw, regp);
}